// Round 4
// baseline (83.467 us; speedup 1.0000x reference)
//
#include <hip/hip_runtime.h>
#include <math.h>

// ROI max-pooling, mirrors the JAX reference exactly.
// features [B=4,C=256,H=64,W=64] f32, rois [N=128,5] f32.
// Output (flat f32): out[N*C*49] then bid[N] (as f32 values).
//
// R4: one wave per (roi, 4 channels). Phase 1 walks rows once in 8-row
// chunks: 32 independent loads in flight per chunk (8 rows x 4 planes),
// using wave-uniform plane bases + 32-bit lane offsets so loads take the
// saddr+voffset form (address VALU shared across channels). 8192 waves
// (~1 residency batch) x ~3 latency waits, vs R3's 2 batches x 6 waits.

#define POOL 7
#define CCH  256   // channels (pow2)
#define FH   64
#define FW   64
#define WPB  4     // waves per block
#define CPW  4     // channels per wave

__global__ __launch_bounds__(256) void roipool_kernel(
    const float* __restrict__ feat,   // [B, C, H, W]
    const float* __restrict__ rois,   // [N, 5]
    float* __restrict__ out,          // [N*C*49 + N]
    int N)
{
    // Per-wave, per-channel column-max staging; inner dim padded 64->65.
    // 4*4*7*65*4 B = 29.1 KB/block -> 5 blocks/CU (enough: 32 waves/CU total).
    __shared__ float smem[WPB][CPW][POOL][65];

    const int wave = threadIdx.x >> 6;
    const int lane = threadIdx.x & 63;
    int task = blockIdx.x * WPB + wave;
    const int ntask = N * (CCH / CPW);     // one wave = one roi x 4 channels
    if (task >= ntask) task = ntask - 1;   // duplicate work; identical writes benign
    const int n  = task >> 6;              // / (CCH/CPW)
    const int c0 = (task & (CCH / CPW - 1)) << 2;

    // ROI decode (uniform across the wave)
    const float* r = rois + (size_t)n * 5;
    const int b  = (int)r[0];
    int px = __float2int_rn(r[1] * 0.0625f);
    int py = __float2int_rn(r[2] * 0.0625f);
    int qx = __float2int_rn(r[3] * 0.0625f);
    int qy = __float2int_rn(r[4] * 0.0625f);
    px = min(max(px, 0), FW - 1); qx = min(max(qx, 0), FW - 1);
    py = min(max(py, 0), FH - 1); qy = min(max(qy, 0), FH - 1);

    const int len_c = max(qx - px + 1, 1);
    const int psz_c = (len_c + POOL - 1) / POOL;
    const int pad_c = (psz_c * POOL - len_c) >> 1;
    const int len_r = max(qy - py + 1, 1);
    const int psz_r = (len_r + POOL - 1) / POOL;
    const int pad_r = (psz_r * POOL - len_r) >> 1;

    const float NEG = -__builtin_huge_valf();

    // Empty (fully-padded) row bins must end up NEG -> 0 in phase 2.
    #pragma unroll
    for (int i = 0; i < POOL; ++i) {
        #pragma unroll
        for (int ch = 0; ch < CPW; ++ch)
            smem[wave][ch][i][lane] = NEG;
    }

    // Wave-uniform plane bases (saddr); lane-varying part stays a 32-bit index.
    const float* p0 = feat + ((size_t)(b * CCH + c0)) * (FH * FW);
    const float* p1 = p0 + FH * FW;
    const float* p2 = p1 + FH * FW;
    const float* p3 = p2 + FH * FW;
    // Lane -> column (clamped duplicate for lanes >= len_c; never read back).
    const int colofs = px + min(lane, len_c - 1);

    // Phase 1: ordered row walk, 8-row chunks, 32 loads in flight.
    int ph = pad_r / psz_r;                          // bin containing row py
    int e  = py - pad_r + (ph + 1) * psz_r - 1;      // last row of bin ph
    float m0 = NEG, m1 = NEG, m2 = NEG, m3 = NEG;

    auto step = [&](int rrk, float a, float bb, float cc, float dd) {
        if (rrk > qy) return;                        // tail mask (uniform)
        m0 = fmaxf(m0, a);  m1 = fmaxf(m1, bb);
        m2 = fmaxf(m2, cc); m3 = fmaxf(m3, dd);
        if (rrk >= e || rrk == qy) {                 // close bin (uniform)
            smem[wave][0][ph][lane] = m0;
            smem[wave][1][ph][lane] = m1;
            smem[wave][2][ph][lane] = m2;
            smem[wave][3][ph][lane] = m3;
            m0 = NEG; m1 = NEG; m2 = NEG; m3 = NEG;
            ++ph; e += psz_r;
        }
    };

    for (int rr = py; rr <= qy; rr += 8) {
        int idx[8];
        #pragma unroll
        for (int k = 0; k < 8; ++k)
            idx[k] = min(rr + k, qy) * FW + colofs;  // clamped: stays in range
        float a[8], bv[8], cv[8], dv[8];
        #pragma unroll
        for (int k = 0; k < 8; ++k) a[k]  = p0[idx[k]];
        #pragma unroll
        for (int k = 0; k < 8; ++k) bv[k] = p1[idx[k]];
        #pragma unroll
        for (int k = 0; k < 8; ++k) cv[k] = p2[idx[k]];
        #pragma unroll
        for (int k = 0; k < 8; ++k) dv[k] = p3[idx[k]];
        #pragma unroll
        for (int k = 0; k < 8; ++k)
            step(rr + k, a[k], bv[k], cv[k], dv[k]);
    }

    __syncthreads();

    // Phase 2: 49 lanes each reduce one (ph, pw) bin's column span, x4 ch.
    if (lane < POOL * POOL) {
        const int bh = lane / POOL;
        const int pw = lane - bh * POOL;
        const int l0 = max(0, pw * psz_c - pad_c);
        const int l1 = min(len_c - 1, (pw + 1) * psz_c - 1 - pad_c);
        const bool hp = (bh * psz_r < pad_r) | ((bh + 1) * psz_r > pad_r + len_r)
                      | (pw * psz_c < pad_c) | ((pw + 1) * psz_c > pad_c + len_c);
        #pragma unroll
        for (int ch = 0; ch < CPW; ++ch) {
            float v = NEG;
            for (int l = l0; l <= l1; ++l)
                v = fmaxf(v, smem[wave][ch][bh][l]);
            if (hp) v = fmaxf(v, 0.0f);              // pad cells compete with 0
            if (!isfinite(v)) v = 0.0f;              // empty bins -> 0
            out[((size_t)n * CCH + c0 + ch) * (POOL * POOL) + lane] = v;
        }
    } else if (lane == POOL * POOL && c0 == 0) {
        // Second tuple output: bid[N], written as f32 values.
        out[(size_t)N * CCH * (POOL * POOL) + n] = (float)b;
    }
}

extern "C" void kernel_launch(void* const* d_in, const int* in_sizes, int n_in,
                              void* d_out, int out_size, void* d_ws, size_t ws_size,
                              hipStream_t stream) {
    const float* feat = (const float*)d_in[0];
    const float* rois = (const float*)d_in[1];
    float* out = (float*)d_out;
    const int N = in_sizes[1] / 5;            // 128
    const int ntask = N * (CCH / CPW);        // one wave per (roi, 4 channels)
    const int blocks = (ntask + WPB - 1) / WPB;
    roipool_kernel<<<blocks, 64 * WPB, 0, stream>>>(feat, rois, out, N);
}

// Round 5
// 80.604 us; speedup vs baseline: 1.0355x; 1.0355x over previous
//
#include <hip/hip_runtime.h>
#include <math.h>

// ROI max-pooling, mirrors the JAX reference exactly.
// features [B=4,C=256,H=64,W=64] f32, rois [N=128,5] f32.
// Output (flat f32): out[N*C*49] then bid[N] (as f32 values).
//
// R5 = R3 (best measured: 81.3 us total; kernel share est. 3-5 us, within
// ~1-2 us of its L2-traffic/latency floor). One wave per (roi, channel-PAIR):
// phase 1 walks rows once in order with 8 independent coalesced loads per
// 4-row chunk (2 channel planes); 14.6 KB LDS -> 8 blocks/CU.
// R4 (4 ch/wave, 8-row chunks, 29 KB LDS) regressed: occupancy 8->5 blocks/CU
// and wasted issue slots on short ROIs outweighed the extra MLP.

#define POOL 7
#define CCH  256   // channels (pow2)
#define FH   64
#define FW   64
#define WPB  4     // waves per block

__global__ __launch_bounds__(256) void roipool_kernel(
    const float* __restrict__ feat,   // [B, C, H, W]
    const float* __restrict__ rois,   // [N, 5]
    float* __restrict__ out,          // [N*C*49 + N]
    int N)
{
    // Per-wave, per-channel column-max staging; inner dim padded 64->65.
    __shared__ float smem[WPB][2][POOL][65];

    const int wave = threadIdx.x >> 6;
    const int lane = threadIdx.x & 63;
    int task = blockIdx.x * WPB + wave;
    const int ntask = N * (CCH / 2);       // one wave = one roi x two channels
    if (task >= ntask) task = ntask - 1;   // duplicate work; identical writes benign
    const int n  = task >> 7;              // / (CCH/2)
    const int c0 = (task & (CCH / 2 - 1)) << 1;

    // ROI decode (uniform across the wave)
    const float* r = rois + (size_t)n * 5;
    const int b  = (int)r[0];
    int px = __float2int_rn(r[1] * 0.0625f);
    int py = __float2int_rn(r[2] * 0.0625f);
    int qx = __float2int_rn(r[3] * 0.0625f);
    int qy = __float2int_rn(r[4] * 0.0625f);
    px = min(max(px, 0), FW - 1); qx = min(max(qx, 0), FW - 1);
    py = min(max(py, 0), FH - 1); qy = min(max(qy, 0), FH - 1);

    const int len_c = max(qx - px + 1, 1);
    const int psz_c = (len_c + POOL - 1) / POOL;
    const int pad_c = (psz_c * POOL - len_c) >> 1;
    const int len_r = max(qy - py + 1, 1);
    const int psz_r = (len_r + POOL - 1) / POOL;
    const int pad_r = (psz_r * POOL - len_r) >> 1;

    const float NEG = -__builtin_huge_valf();

    // Empty (fully-padded) row bins must end up NEG -> 0 in phase 2.
    #pragma unroll
    for (int i = 0; i < POOL; ++i) {
        smem[wave][0][i][lane] = NEG;
        smem[wave][1][i][lane] = NEG;
    }

    // Lane -> feature column (clamped duplicate for lanes >= len_c; phase 2
    // never reads their smem slots, and duplicates hit the same cache line,
    // so line-granular L2 traffic only covers px..qx).
    const int colofs = px + min(lane, len_c - 1);
    const float* base0 = feat + ((size_t)(b * CCH + c0)) * (FH * FW) + colofs;
    const float* base1 = base0 + FH * FW;

    // Phase 1: single ordered row walk; bins are consecutive row ranges, so
    // keep running maxes and close a bin at its (wave-uniform) end row.
    // 8 independent loads per 4-row chunk keep the memory pipe full.
    int ph = pad_r / psz_r;                          // bin containing row py
    int e  = py - pad_r + (ph + 1) * psz_r - 1;      // last row of bin ph
    float m0 = NEG, m1 = NEG;

    auto step = [&](int rrk, float a, float bb) {
        if (rrk > qy) return;                        // tail mask (uniform)
        m0 = fmaxf(m0, a);
        m1 = fmaxf(m1, bb);
        if (rrk >= e || rrk == qy) {                 // close bin (uniform)
            smem[wave][0][ph][lane] = m0;
            smem[wave][1][ph][lane] = m1;
            m0 = NEG; m1 = NEG; ++ph; e += psz_r;
        }
    };

    for (int rr = py; rr <= qy; rr += 4) {
        const int o0 = rr * FW;
        const int o1 = min(rr + 1, qy) * FW;
        const int o2 = min(rr + 2, qy) * FW;
        const int o3 = min(rr + 3, qy) * FW;
        float a0 = base0[o0], a1 = base0[o1], a2 = base0[o2], a3 = base0[o3];
        float b0 = base1[o0], b1 = base1[o1], b2 = base1[o2], b3 = base1[o3];
        step(rr,     a0, b0);
        step(rr + 1, a1, b1);
        step(rr + 2, a2, b2);
        step(rr + 3, a3, b3);
    }

    __syncthreads();

    // Phase 2: 49 lanes each reduce one (ph, pw) bin's column span, x2 channels.
    if (lane < POOL * POOL) {
        const int bh = lane / POOL;
        const int pw = lane - bh * POOL;
        const int l0 = max(0, pw * psz_c - pad_c);
        const int l1 = min(len_c - 1, (pw + 1) * psz_c - 1 - pad_c);
        const bool hp = (bh * psz_r < pad_r) | ((bh + 1) * psz_r > pad_r + len_r)
                      | (pw * psz_c < pad_c) | ((pw + 1) * psz_c > pad_c + len_c);
        #pragma unroll
        for (int ch = 0; ch < 2; ++ch) {
            float v = NEG;
            for (int l = l0; l <= l1; ++l)
                v = fmaxf(v, smem[wave][ch][bh][l]);
            if (hp) v = fmaxf(v, 0.0f);              // pad cells compete with 0
            if (!isfinite(v)) v = 0.0f;              // empty bins -> 0
            out[((size_t)n * CCH + c0 + ch) * (POOL * POOL) + lane] = v;
        }
    } else if (lane == POOL * POOL && c0 == 0) {
        // Second tuple output: bid[N], written as f32 values.
        out[(size_t)N * CCH * (POOL * POOL) + n] = (float)b;
    }
}

extern "C" void kernel_launch(void* const* d_in, const int* in_sizes, int n_in,
                              void* d_out, int out_size, void* d_ws, size_t ws_size,
                              hipStream_t stream) {
    const float* feat = (const float*)d_in[0];
    const float* rois = (const float*)d_in[1];
    float* out = (float*)d_out;
    const int N = in_sizes[1] / 5;            // 128
    const int ntask = N * (CCH / 2);          // one wave per (roi, channel pair)
    const int blocks = (ntask + WPB - 1) / WPB;
    roipool_kernel<<<blocks, 64 * WPB, 0, stream>>>(feat, rois, out, N);
}